// Round 1
// baseline (399.980 us; speedup 1.0000x reference)
//
#include <hip/hip_runtime.h>
#include <hip/hip_bf16.h>

#define HW 16384
#define NB 8
#define NC 192
#define NC3 576
#define NHEADS 4
#define CPH 48

typedef __attribute__((ext_vector_type(8))) short short8v;
typedef __attribute__((ext_vector_type(4))) float f32x4;

__device__ __forceinline__ float bf2f(ushort u) {
    union { unsigned int u; float f; } w; w.u = ((unsigned int)u) << 16; return w.f;
}
__device__ __forceinline__ ushort f2bf(float f) {
    union { float f; unsigned int u; } w; w.f = f;
    return (ushort)((w.u + 0x7FFFu + ((w.u >> 16) & 1u)) >> 16);
}

// ---------------- prep: convert w_in (576x192 f32) to bf16 ----------------
__global__ __launch_bounds__(256) void k_prep(const float* __restrict__ w_in,
                                              ushort* __restrict__ w_bf) {
    int i = blockIdx.x * 256 + threadIdx.x;
    if (i < NC3 * NC) w_bf[i] = f2bf(w_in[i]);
}

// ---------------- GEMM: Out[b][m][n] = sum_k A[b][m][k] * B[b][k][n] ------
// K fixed = 192. Tile 64x64, 4 waves (2x2), each wave 32x32 via 2x2 MFMA frags.
template<bool A_F32, bool B_F32, bool OUT_F32>
__global__ __launch_bounds__(256) void k_gemm(
    const void* __restrict__ Ap, long aStride,
    const void* __restrict__ Bp, long bStride,
    void* __restrict__ Op, long oStride)
{
    __shared__ short8v AsV[64][25];   // 64 rows x 200 ushort (192 + 8 pad)
    __shared__ short8v BsV[64][25];   // Bs[n][k] (transposed)
    ushort* As = (ushort*)AsV;
    ushort* Bs = (ushort*)BsV;
    const int t = threadIdx.x;
    const int mt = blockIdx.x, nt = blockIdx.y, b = blockIdx.z;

    // ---- stage A rows [mt*64, mt*64+64) x k[0,192)
    {
        int row = t >> 2;             // 0..63
        int kb  = (t & 3) * 48;
        if constexpr (A_F32) {
            const float* A = (const float*)Ap + (long)b * aStride
                           + ((long)(mt * 64 + row)) * NC + kb;
            #pragma unroll
            for (int i = 0; i < 48; i += 4) {
                float4 v = *(const float4*)(A + i);
                ushort* d = As + row * 200 + kb + i;
                d[0] = f2bf(v.x); d[1] = f2bf(v.y); d[2] = f2bf(v.z); d[3] = f2bf(v.w);
            }
        } else {
            const ushort* A = (const ushort*)Ap + (long)b * aStride
                            + ((long)(mt * 64 + row)) * NC + kb;
            #pragma unroll
            for (int i = 0; i < 48; i += 8)
                *(short8v*)(As + row * 200 + kb + i) = *(const short8v*)(A + i);
        }
    }
    // ---- stage B transposed: Bs[n][k] = B[k][nt*64+n]
    {
        int nl = (t & 15) * 4;        // 4 consecutive n
        int k0 = t >> 4;              // 0..15
        #pragma unroll
        for (int kk = 0; kk < 12; kk++) {
            int k = k0 + kk * 16;
            if constexpr (B_F32) {
                const float* Bb = (const float*)Bp + (long)b * bStride
                                + (long)k * HW + nt * 64 + nl;
                float4 v = *(const float4*)Bb;
                Bs[(nl + 0) * 200 + k] = f2bf(v.x);
                Bs[(nl + 1) * 200 + k] = f2bf(v.y);
                Bs[(nl + 2) * 200 + k] = f2bf(v.z);
                Bs[(nl + 3) * 200 + k] = f2bf(v.w);
            } else {
                const ushort* Bb = (const ushort*)Bp + (long)b * bStride
                                 + (long)k * HW + nt * 64 + nl;
                ushort4 v = *(const ushort4*)Bb;
                Bs[(nl + 0) * 200 + k] = v.x;
                Bs[(nl + 1) * 200 + k] = v.y;
                Bs[(nl + 2) * 200 + k] = v.z;
                Bs[(nl + 3) * 200 + k] = v.w;
            }
        }
    }
    __syncthreads();

    const int wid = t >> 6, lane = t & 63;
    const int wm = (wid >> 1) * 32, wn = (wid & 1) * 32;
    const int lr = lane & 15, lk = lane >> 4;
    const f32x4 z4 = {0.f, 0.f, 0.f, 0.f};
    f32x4 acc[2][2];
    acc[0][0] = z4; acc[0][1] = z4; acc[1][0] = z4; acc[1][1] = z4;

    #pragma unroll
    for (int k8 = 0; k8 < 24; k8 += 4) {   // k = k8*8, step 32 elements
        short8v a0 = AsV[wm + lr][k8 + lk];
        short8v a1 = AsV[wm + 16 + lr][k8 + lk];
        short8v b0 = BsV[wn + lr][k8 + lk];
        short8v b1 = BsV[wn + 16 + lr][k8 + lk];
        acc[0][0] = __builtin_amdgcn_mfma_f32_16x16x32_bf16(a0, b0, acc[0][0], 0, 0, 0);
        acc[0][1] = __builtin_amdgcn_mfma_f32_16x16x32_bf16(a0, b1, acc[0][1], 0, 0, 0);
        acc[1][0] = __builtin_amdgcn_mfma_f32_16x16x32_bf16(a1, b0, acc[1][0], 0, 0, 0);
        acc[1][1] = __builtin_amdgcn_mfma_f32_16x16x32_bf16(a1, b1, acc[1][1], 0, 0, 0);
    }
    // D layout: col = lane&15, row = (lane>>4)*4 + r
    #pragma unroll
    for (int mi = 0; mi < 2; mi++) {
        #pragma unroll
        for (int ni = 0; ni < 2; ni++) {
            long gm = (long)mt * 64 + wm + mi * 16 + lk * 4;
            long gn = (long)nt * 64 + wn + ni * 16 + lr;
            if constexpr (OUT_F32) {
                float* O = (float*)Op + (long)b * oStride + gm * HW + gn;
                #pragma unroll
                for (int r = 0; r < 4; r++) O[(long)r * HW] = acc[mi][ni][r];
            } else {
                ushort* O = (ushort*)Op + (long)b * oStride + gm * HW + gn;
                #pragma unroll
                for (int r = 0; r < 4; r++) O[(long)r * HW] = f2bf(acc[mi][ni][r]);
            }
        }
    }
}

// ---------------- depthwise 3x3 (pad 1) + sumsq for q/k rows --------------
// one block per (b, channel) 128x128 plane
__global__ __launch_bounds__(256) void k_dwconv(
    const ushort* __restrict__ qkv, const float* __restrict__ w_dw,
    ushort* __restrict__ qkv_dw, float* __restrict__ sumsq)
{
    __shared__ ushort tile[130 * 144];  // rows 0..129 (halo), col layout: [7]=left halo, [8..135]=cols, [136]=right halo
    __shared__ float red[4];
    const int t = threadIdx.x;
    const int c = blockIdx.x, b = blockIdx.y;

    // zero whole tile (halo + pad become zeros)
    unsigned int* tz = (unsigned int*)tile;
    for (int i = t; i < (130 * 144) / 2; i += 256) tz[i] = 0u;
    __syncthreads();

    const ushort* src = qkv + ((long)b * NC3 + c) * HW;
    #pragma unroll
    for (int i = 0; i < 8; i++) {
        int idx = t + 256 * i;        // short8 index 0..2047
        int row = idx >> 4;           // 16 short8 per 128-col row
        int col8 = idx & 15;
        *(short8v*)(tile + (row + 1) * 144 + 8 + col8 * 8) =
            *(const short8v*)(src + (long)idx * 8);
    }
    __syncthreads();

    float wv[9];
    #pragma unroll
    for (int j = 0; j < 9; j++) wv[j] = w_dw[c * 9 + j];

    const int cb = (t & 31) * 4;      // 4 consecutive output cols
    const int r0 = (t >> 5) * 16;     // 16 consecutive output rows
    ushort* dst = qkv_dw + ((long)b * NC3 + c) * HW;
    float ssq = 0.f;

    for (int rr = 0; rr < 16; rr++) {
        int r = r0 + rr;
        float in[3][12];
        #pragma unroll
        for (int dr = 0; dr < 3; dr++) {
            const ushort* lp = tile + (r + dr) * 144 + 8 + cb - 4;
            #pragma unroll
            for (int q4 = 0; q4 < 3; q4++) {
                ushort4 v = *(const ushort4*)(lp + q4 * 4);
                in[dr][q4 * 4 + 0] = bf2f(v.x);
                in[dr][q4 * 4 + 1] = bf2f(v.y);
                in[dr][q4 * 4 + 2] = bf2f(v.z);
                in[dr][q4 * 4 + 3] = bf2f(v.w);
            }
        }
        ushort4 o4;
        #pragma unroll
        for (int oc = 0; oc < 4; oc++) {
            float a = 0.f;
            #pragma unroll
            for (int dr = 0; dr < 3; dr++) {
                #pragma unroll
                for (int dc = 0; dc < 3; dc++)
                    a += in[dr][3 + oc + dc] * wv[dr * 3 + dc];
            }
            ssq += a * a;
            ushort ob = f2bf(a);
            if (oc == 0) o4.x = ob; else if (oc == 1) o4.y = ob;
            else if (oc == 2) o4.z = ob; else o4.w = ob;
        }
        *(ushort4*)(dst + (long)r * 128 + cb) = o4;
    }

    // block-reduce ssq; one block owns the whole plane -> direct store
    #pragma unroll
    for (int off = 32; off > 0; off >>= 1) ssq += __shfl_down(ssq, off, 64);
    if ((t & 63) == 0) red[t >> 6] = ssq;
    __syncthreads();
    if (t == 0 && c < 2 * NC) sumsq[b * (2 * NC) + c] = red[0] + red[1] + red[2] + red[3];
}

// ---------------- attention scores: partial S = q . k^T -------------------
// grid (32 bh, 8 ksplit); both MFMA operands read straight from global
__global__ __launch_bounds__(256) void k_scores(
    const ushort* __restrict__ qkv_dw, float* __restrict__ Spart)
{
    const int bh = blockIdx.x, ks = blockIdx.y;
    const int b = bh >> 2, h = bh & 3;
    const int t = threadIdx.x, wid = t >> 6, lane = t & 63;
    const int lr = lane & 15, lk = lane >> 4;
    const ushort* qb = qkv_dw + ((long)b * NC3 + h * CPH) * HW;
    const ushort* kb = qb + (long)NC * HW;

    const f32x4 z4 = {0.f, 0.f, 0.f, 0.f};
    f32x4 acc[3][3];
    #pragma unroll
    for (int i = 0; i < 3; i++) {
        #pragma unroll
        for (int j = 0; j < 3; j++) acc[i][j] = z4;
    }

    const int kstart = ks * 2048 + wid * 512;
    for (int k0 = kstart; k0 < kstart + 512; k0 += 32) {
        short8v a[3], bv[3];
        #pragma unroll
        for (int i = 0; i < 3; i++) {
            a[i]  = *(const short8v*)(qb + (long)(i * 16 + lr) * HW + k0 + lk * 8);
            bv[i] = *(const short8v*)(kb + (long)(i * 16 + lr) * HW + k0 + lk * 8);
        }
        #pragma unroll
        for (int mi = 0; mi < 3; mi++) {
            #pragma unroll
            for (int ni = 0; ni < 3; ni++)
                acc[mi][ni] = __builtin_amdgcn_mfma_f32_16x16x32_bf16(a[mi], bv[ni], acc[mi][ni], 0, 0, 0);
        }
    }

    __shared__ float Sb[4 * 48 * 48];
    #pragma unroll
    for (int mi = 0; mi < 3; mi++) {
        #pragma unroll
        for (int ni = 0; ni < 3; ni++) {
            #pragma unroll
            for (int r = 0; r < 4; r++)
                Sb[wid * 2304 + (mi * 16 + lk * 4 + r) * 48 + ni * 16 + lr] = acc[mi][ni][r];
        }
    }
    __syncthreads();
    float* outp = Spart + ((long)ks * 32 + bh) * 2304;
    for (int i = t; i < 2304; i += 256)
        outp[i] = Sb[i] + Sb[2304 + i] + Sb[4608 + i] + Sb[6912 + i];
}

// ------- finalize: reduce partials, normalize, softmax, fold w_out --------
__global__ __launch_bounds__(256) void k_final(
    const float* __restrict__ Spart, const float* __restrict__ sumsq,
    const float* __restrict__ temperature, const float* __restrict__ wout,
    ushort* __restrict__ Mmat)
{
    const int bh = blockIdx.x, b = bh >> 2, h = bh & 3;
    const int t = threadIdx.x;
    __shared__ float S[48 * 48];
    __shared__ float P[48 * 48];
    __shared__ float invq[48], invk[48];
    if (t < 48) {
        invq[t] = 1.f / fmaxf(sqrtf(sumsq[b * (2 * NC) + h * CPH + t]), 1e-12f);
        invk[t] = 1.f / fmaxf(sqrtf(sumsq[b * (2 * NC) + NC + h * CPH + t]), 1e-12f);
    }
    __syncthreads();
    const float T = temperature[h];
    for (int i = t; i < 2304; i += 256) {
        float s = 0.f;
        #pragma unroll
        for (int p = 0; p < 8; p++) s += Spart[((long)p * 32 + bh) * 2304 + i];
        int cc = i / 48, dd = i - cc * 48;
        S[i] = s * invq[cc] * invk[dd] * T;
    }
    __syncthreads();
    if (t < 48) {
        float m = -1e30f;
        for (int d = 0; d < 48; d++) m = fmaxf(m, S[t * 48 + d]);
        float sum = 0.f;
        for (int d = 0; d < 48; d++) { float e = __expf(S[t * 48 + d] - m); P[t * 48 + d] = e; sum += e; }
        float inv = 1.f / sum;
        for (int d = 0; d < 48; d++) P[t * 48 + d] *= inv;
    }
    __syncthreads();
    // M[o][h*48+d] = sum_c wout[o][h*48+c] * P[c][d]
    for (int i = t; i < NC * CPH; i += 256) {
        int o = i / 48, d = i - (i / 48) * 48;
        float a = 0.f;
        for (int c2 = 0; c2 < 48; c2++)
            a += wout[o * NC + h * CPH + c2] * P[c2 * 48 + d];
        Mmat[(long)b * NC * NC + (long)o * NC + h * CPH + d] = f2bf(a);
    }
}

// --------------------------------------------------------------------------
extern "C" void kernel_launch(void* const* d_in, const int* in_sizes, int n_in,
                              void* d_out, int out_size, void* d_ws, size_t ws_size,
                              hipStream_t stream)
{
    (void)in_sizes; (void)n_in; (void)out_size;
    const float* x     = (const float*)d_in[0];
    const float* w_in  = (const float*)d_in[1];
    const float* w_dw  = (const float*)d_in[2];
    const float* temp  = (const float*)d_in[3];
    const float* w_out = (const float*)d_in[4];
    float* outp = (float*)d_out;

    // workspace layout (bytes)
    const long QKV_BYTES = (long)NB * NC3 * HW * 2;      // 150,994,944
    char* ws = (char*)d_ws;
    if (ws_size < 305172480UL) return;                   // graceful bail
    ushort* qkv    = (ushort*)(ws);
    ushort* qkv_dw = (ushort*)(ws + QKV_BYTES);
    ushort* w_bf   = (ushort*)(ws + 2 * QKV_BYTES);            // 221,184 B
    float*  sumsq  = (float*) (ws + 302211072L);               // 12,288 B
    float*  Spart  = (float*) (ws + 302223360L);               // 2,359,296 B
    ushort* Mmat   = (ushort*)(ws + 304582656L);               // 589,824 B

    k_prep<<<dim3(432), 256, 0, stream>>>(w_in, w_bf);

    // conv_in: qkv[b][o][n] = sum_c w_in[o][c] x[b][c][n]
    k_gemm<false, true, false><<<dim3(9, 256, NB), 256, 0, stream>>>(
        w_bf, 0L, x, (long)NC * HW, qkv, (long)NC3 * HW);

    k_dwconv<<<dim3(NC3, NB), 256, 0, stream>>>(qkv, w_dw, qkv_dw, sumsq);

    k_scores<<<dim3(32, 8), 256, 0, stream>>>(qkv_dw, Spart);

    k_final<<<dim3(32), 256, 0, stream>>>(Spart, sumsq, temp, w_out, Mmat);

    // out[b] = M[b] (192x192) @ v[b] (192 x HW)
    k_gemm<false, false, true><<<dim3(3, 256, NB), 256, 0, stream>>>(
        Mmat, (long)NC * NC, qkv_dw + (long)(2 * NC) * HW, (long)NC3 * HW,
        outp, (long)NC * HW);
}

// Round 3
// 301.103 us; speedup vs baseline: 1.3284x; 1.3284x over previous
//
#include <hip/hip_runtime.h>
#include <hip/hip_bf16.h>

#define HW 16384
#define NB 8
#define NC 192
#define NC3 576
#define NHEADS 4
#define CPH 48

typedef __attribute__((ext_vector_type(8))) short short8v;
typedef __attribute__((ext_vector_type(4))) float f32x4;

__device__ __forceinline__ float bf2f(ushort u) {
    union { unsigned int u; float f; } w; w.u = ((unsigned int)u) << 16; return w.f;
}
__device__ __forceinline__ ushort f2bf(float f) {
    union { float f; unsigned int u; } w; w.f = f;
    return (ushort)((w.u + 0x7FFFu + ((w.u >> 16) & 1u)) >> 16);
}

// ---------------- prep: convert w_in (576x192 f32) to bf16 ----------------
__global__ __launch_bounds__(256) void k_prep(const float* __restrict__ w_in,
                                              ushort* __restrict__ w_bf) {
    int i = blockIdx.x * 256 + threadIdx.x;
    if (i < NC3 * NC) w_bf[i] = f2bf(w_in[i]);
}

// ---------------- GEMM v2: B-tile stationary in LDS, loop over o-tiles ----
// Out[b][m][n] = sum_k A[b][m][k] * B[b][k][n],  K = 192, M = MT*64.
// A rows are k-contiguous bf16 -> fragments read DIRECTLY from global (L2-hot).
// B tile (192k x 64n) staged transposed in LDS once per block.
template<bool B_F32, bool OUT_F32>
__global__ __launch_bounds__(256) void k_gemm2(
    const ushort* __restrict__ Abase, long aStride, int MT,
    const void* __restrict__ Bp, long bStride,
    void* __restrict__ Op, long oStride)
{
    __shared__ ushort Bs[64 * 200];   // row = n (0..63), pitch 200 ushort
    const int t = threadIdx.x;
    const int nt = blockIdx.x, b = blockIdx.y;

    // ---- stage B transposed: Bs[n][k] = B[k][nt*64+n], reg-transpose 4n x 12k
    {
        const int n0 = (t & 15) * 4;
        const int k0 = (t >> 4) * 12;
        ushort vals[12][4];
        if constexpr (B_F32) {
            const float* B = (const float*)Bp + (long)b * bStride
                           + (long)k0 * HW + nt * 64 + n0;
            #pragma unroll
            for (int kk = 0; kk < 12; kk++) {
                float4 v = *(const float4*)(B + (long)kk * HW);
                vals[kk][0] = f2bf(v.x); vals[kk][1] = f2bf(v.y);
                vals[kk][2] = f2bf(v.z); vals[kk][3] = f2bf(v.w);
            }
        } else {
            const ushort* B = (const ushort*)Bp + (long)b * bStride
                            + (long)k0 * HW + nt * 64 + n0;
            #pragma unroll
            for (int kk = 0; kk < 12; kk++) {
                ushort4 v = *(const ushort4*)(B + (long)kk * HW);
                vals[kk][0] = v.x; vals[kk][1] = v.y;
                vals[kk][2] = v.z; vals[kk][3] = v.w;
            }
        }
        #pragma unroll
        for (int i = 0; i < 4; i++) {
            #pragma unroll
            for (int seg = 0; seg < 3; seg++) {
                ushort4 w4;
                w4.x = vals[seg * 4 + 0][i];
                w4.y = vals[seg * 4 + 1][i];
                w4.z = vals[seg * 4 + 2][i];
                w4.w = vals[seg * 4 + 3][i];
                *(ushort4*)&Bs[(n0 + i) * 200 + k0 + seg * 4] = w4;
            }
        }
    }
    __syncthreads();

    const int wid = t >> 6, lane = t & 63;
    const int wm = (wid >> 1) * 32, wn = (wid & 1) * 32;
    const int lr = lane & 15, lk = lane >> 4;
    const ushort* Ab = Abase + (long)b * aStride;
    const ushort* Bs0 = &Bs[(wn + lr) * 200 + lk * 8];
    const f32x4 z4 = {0.f, 0.f, 0.f, 0.f};

    for (int ot = 0; ot < MT; ot++) {
        f32x4 acc[2][2];
        acc[0][0] = z4; acc[0][1] = z4; acc[1][0] = z4; acc[1][1] = z4;
        const ushort* Ar0 = Ab + (long)(ot * 64 + wm + lr) * NC + lk * 8;
        const ushort* Ar1 = Ar0 + 16 * NC;
        #pragma unroll
        for (int ks = 0; ks < 6; ks++) {
            short8v a0 = *(const short8v*)(Ar0 + ks * 32);
            short8v a1 = *(const short8v*)(Ar1 + ks * 32);
            short8v b0 = *(const short8v*)(Bs0 + ks * 32);
            short8v b1 = *(const short8v*)(Bs0 + 16 * 200 + ks * 32);
            acc[0][0] = __builtin_amdgcn_mfma_f32_16x16x32_bf16(a0, b0, acc[0][0], 0, 0, 0);
            acc[0][1] = __builtin_amdgcn_mfma_f32_16x16x32_bf16(a0, b1, acc[0][1], 0, 0, 0);
            acc[1][0] = __builtin_amdgcn_mfma_f32_16x16x32_bf16(a1, b0, acc[1][0], 0, 0, 0);
            acc[1][1] = __builtin_amdgcn_mfma_f32_16x16x32_bf16(a1, b1, acc[1][1], 0, 0, 0);
        }
        // D layout: col = lane&15, row = (lane>>4)*4 + r
        #pragma unroll
        for (int mi = 0; mi < 2; mi++) {
            #pragma unroll
            for (int ni = 0; ni < 2; ni++) {
                long gm = (long)ot * 64 + wm + mi * 16 + lk * 4;
                long gn = (long)nt * 64 + wn + ni * 16 + lr;
                if constexpr (OUT_F32) {
                    float* O = (float*)Op + (long)b * oStride + gm * HW + gn;
                    #pragma unroll
                    for (int r = 0; r < 4; r++) O[(long)r * HW] = acc[mi][ni][r];
                } else {
                    ushort* O = (ushort*)Op + (long)b * oStride + gm * HW + gn;
                    #pragma unroll
                    for (int r = 0; r < 4; r++) O[(long)r * HW] = f2bf(acc[mi][ni][r]);
                }
            }
        }
    }
}

// ---------------- depthwise 3x3 (pad 1) + sumsq for q/k rows --------------
// one block per (b, channel) 128x128 plane; rolling 3-row window, 8-wide strips
__global__ __launch_bounds__(256) void k_dwconv(
    const ushort* __restrict__ qkv, const float* __restrict__ w_dw,
    ushort* __restrict__ qkv_dw, float* __restrict__ sumsq)
{
    __shared__ ushort tile[130 * 144];  // row r+1 holds plane row r; col 8+c holds plane col c
    __shared__ float red[4];
    const int t = threadIdx.x;
    const int c = blockIdx.x, b = blockIdx.y;

    // zero only the halo (top/bottom rows + left/right cols)
    if (t < 144) { tile[t] = 0; tile[129 * 144 + t] = 0; }
    if (t < 128) { tile[(t + 1) * 144 + 7] = 0; tile[(t + 1) * 144 + 136] = 0; }

    // load interior (disjoint from halo; single barrier after)
    const ushort* src = qkv + ((long)b * NC3 + c) * HW;
    #pragma unroll
    for (int i = 0; i < 8; i++) {
        int idx = t + 256 * i;        // short8 index 0..2047
        int row = idx >> 4;
        int col8 = idx & 15;
        *(short8v*)(tile + (row + 1) * 144 + 8 + col8 * 8) =
            *(const short8v*)(src + (long)idx * 8);
    }
    __syncthreads();

    float wv[9];
    #pragma unroll
    for (int j = 0; j < 9; j++) wv[j] = w_dw[c * 9 + j];

    const int cb = (t & 15) * 8;      // 8 consecutive output cols
    const int r0 = (t >> 4) * 8;      // 8 consecutive output rows
    float win[3][16];                 // window: plane cols cb-4 .. cb+11

    auto load_row = [&](int tr, int slot) {
        #pragma unroll
        for (int j = 0; j < 4; j++) {
            ushort4 v = *(const ushort4*)(tile + tr * 144 + 4 + cb + j * 4);
            win[slot][j * 4 + 0] = bf2f(v.x);
            win[slot][j * 4 + 1] = bf2f(v.y);
            win[slot][j * 4 + 2] = bf2f(v.z);
            win[slot][j * 4 + 3] = bf2f(v.w);
        }
    };

    load_row(r0, 0);          // input row r0-1 (tile row r0)
    load_row(r0 + 1, 1);      // input row r0
    float ssq = 0.f;
    ushort* dst = qkv_dw + ((long)b * NC3 + c) * HW + (long)r0 * 128 + cb;

    #pragma unroll
    for (int rr = 0; rr < 8; rr++) {
        load_row(r0 + rr + 2, (rr + 2) % 3);
        const int s0 = rr % 3, s1 = (rr + 1) % 3, s2 = (rr + 2) % 3;
        short8v o;
        #pragma unroll
        for (int oc = 0; oc < 8; oc++) {
            float a = win[s0][oc + 3] * wv[0] + win[s0][oc + 4] * wv[1] + win[s0][oc + 5] * wv[2]
                    + win[s1][oc + 3] * wv[3] + win[s1][oc + 4] * wv[4] + win[s1][oc + 5] * wv[5]
                    + win[s2][oc + 3] * wv[6] + win[s2][oc + 4] * wv[7] + win[s2][oc + 5] * wv[8];
            ssq += a * a;
            o[oc] = (short)f2bf(a);
        }
        *(short8v*)(dst + rr * 128) = o;
    }

    // block-reduce ssq; one block owns the whole plane -> direct store
    #pragma unroll
    for (int off = 32; off > 0; off >>= 1) ssq += __shfl_down(ssq, off, 64);
    if ((t & 63) == 0) red[t >> 6] = ssq;
    __syncthreads();
    if (t == 0 && c < 2 * NC) sumsq[b * (2 * NC) + c] = red[0] + red[1] + red[2] + red[3];
}

// ---------------- attention scores: partial S = q . k^T -------------------
// grid (32 bh, 8 ksplit); both MFMA operands read straight from global
__global__ __launch_bounds__(256) void k_scores(
    const ushort* __restrict__ qkv_dw, float* __restrict__ Spart)
{
    const int bh = blockIdx.x, ks = blockIdx.y;
    const int b = bh >> 2, h = bh & 3;
    const int t = threadIdx.x, wid = t >> 6, lane = t & 63;
    const int lr = lane & 15, lk = lane >> 4;
    const ushort* qb = qkv_dw + ((long)b * NC3 + h * CPH) * HW;
    const ushort* kb = qb + (long)NC * HW;

    const f32x4 z4 = {0.f, 0.f, 0.f, 0.f};
    f32x4 acc[3][3];
    #pragma unroll
    for (int i = 0; i < 3; i++) {
        #pragma unroll
        for (int j = 0; j < 3; j++) acc[i][j] = z4;
    }

    const int kstart = ks * 2048 + wid * 512;
    for (int k0 = kstart; k0 < kstart + 512; k0 += 32) {
        short8v a[3], bv[3];
        #pragma unroll
        for (int i = 0; i < 3; i++) {
            a[i]  = *(const short8v*)(qb + (long)(i * 16 + lr) * HW + k0 + lk * 8);
            bv[i] = *(const short8v*)(kb + (long)(i * 16 + lr) * HW + k0 + lk * 8);
        }
        #pragma unroll
        for (int mi = 0; mi < 3; mi++) {
            #pragma unroll
            for (int ni = 0; ni < 3; ni++)
                acc[mi][ni] = __builtin_amdgcn_mfma_f32_16x16x32_bf16(a[mi], bv[ni], acc[mi][ni], 0, 0, 0);
        }
    }

    __shared__ float Sb[4 * 48 * 48];
    #pragma unroll
    for (int mi = 0; mi < 3; mi++) {
        #pragma unroll
        for (int ni = 0; ni < 3; ni++) {
            #pragma unroll
            for (int r = 0; r < 4; r++)
                Sb[wid * 2304 + (mi * 16 + lk * 4 + r) * 48 + ni * 16 + lr] = acc[mi][ni][r];
        }
    }
    __syncthreads();
    float* outp = Spart + ((long)ks * 32 + bh) * 2304;
    for (int i = t; i < 2304; i += 256)
        outp[i] = Sb[i] + Sb[2304 + i] + Sb[4608 + i] + Sb[6912 + i];
}

// ------- finalize: reduce partials, normalize, softmax, fold w_out --------
__global__ __launch_bounds__(256) void k_final(
    const float* __restrict__ Spart, const float* __restrict__ sumsq,
    const float* __restrict__ temperature, const float* __restrict__ wout,
    ushort* __restrict__ Mmat)
{
    const int bh = blockIdx.x, b = bh >> 2, h = bh & 3;
    const int t = threadIdx.x;
    __shared__ float S[48 * 48];
    __shared__ float P[48 * 48];
    __shared__ float invq[48], invk[48];
    if (t < 48) {
        invq[t] = 1.f / fmaxf(sqrtf(sumsq[b * (2 * NC) + h * CPH + t]), 1e-12f);
        invk[t] = 1.f / fmaxf(sqrtf(sumsq[b * (2 * NC) + NC + h * CPH + t]), 1e-12f);
    }
    __syncthreads();
    const float T = temperature[h];
    for (int i = t; i < 2304; i += 256) {
        float s = 0.f;
        #pragma unroll
        for (int p = 0; p < 8; p++) s += Spart[((long)p * 32 + bh) * 2304 + i];
        int cc = i / 48, dd = i - cc * 48;
        S[i] = s * invq[cc] * invk[dd] * T;
    }
    __syncthreads();
    if (t < 48) {
        float m = -1e30f;
        for (int d = 0; d < 48; d++) m = fmaxf(m, S[t * 48 + d]);
        float sum = 0.f;
        for (int d = 0; d < 48; d++) { float e = __expf(S[t * 48 + d] - m); P[t * 48 + d] = e; sum += e; }
        float inv = 1.f / sum;
        for (int d = 0; d < 48; d++) P[t * 48 + d] *= inv;
    }
    __syncthreads();
    // M[o][h*48+d] = sum_c wout[o][h*48+c] * P[c][d]
    for (int i = t; i < NC * CPH; i += 256) {
        int o = i / 48, d = i - (i / 48) * 48;
        float a = 0.f;
        for (int c2 = 0; c2 < 48; c2++)
            a += wout[o * NC + h * CPH + c2] * P[c2 * 48 + d];
        Mmat[(long)b * NC * NC + (long)o * NC + h * CPH + d] = f2bf(a);
    }
}

// --------------------------------------------------------------------------
extern "C" void kernel_launch(void* const* d_in, const int* in_sizes, int n_in,
                              void* d_out, int out_size, void* d_ws, size_t ws_size,
                              hipStream_t stream)
{
    (void)in_sizes; (void)n_in; (void)out_size;
    const float* x     = (const float*)d_in[0];
    const float* w_in  = (const float*)d_in[1];
    const float* w_dw  = (const float*)d_in[2];
    const float* temp  = (const float*)d_in[3];
    const float* w_out = (const float*)d_in[4];
    float* outp = (float*)d_out;

    // workspace layout (bytes)
    const long QKV_BYTES = (long)NB * NC3 * HW * 2;      // 150,994,944
    char* ws = (char*)d_ws;
    if (ws_size < 305172480UL) return;                   // graceful bail
    ushort* qkv    = (ushort*)(ws);
    ushort* qkv_dw = (ushort*)(ws + QKV_BYTES);
    ushort* w_bf   = (ushort*)(ws + 2 * QKV_BYTES);            // 221,184 B
    float*  sumsq  = (float*) (ws + 302211072L);               // 12,288 B
    float*  Spart  = (float*) (ws + 302223360L);               // 2,359,296 B
    ushort* Mmat   = (ushort*)(ws + 304582656L);               // 589,824 B

    k_prep<<<dim3(432), 256, 0, stream>>>(w_in, w_bf);

    // conv_in: qkv[b][o][n] = sum_c w_in[o][c] x[b][c][n]; A = w_bf (aStride 0)
    k_gemm2<true, false><<<dim3(256, NB), 256, 0, stream>>>(
        w_bf, 0L, 9, x, (long)NC * HW, qkv, (long)NC3 * HW);

    k_dwconv<<<dim3(NC3, NB), 256, 0, stream>>>(qkv, w_dw, qkv_dw, sumsq);

    k_scores<<<dim3(32, 8), 256, 0, stream>>>(qkv_dw, Spart);

    k_final<<<dim3(32), 256, 0, stream>>>(Spart, sumsq, temp, w_out, Mmat);

    // out[b] = M[b] (192x192) @ v[b] (192 x HW)
    k_gemm2<false, true><<<dim3(256, NB), 256, 0, stream>>>(
        Mmat, (long)NC * NC, 3, qkv_dw + (long)(2 * NC) * HW, (long)NC3 * HW,
        outp, (long)NC * HW);
}